// Round 18
// baseline (250.270 us; speedup 1.0000x reference)
//
#include <hip/hip_runtime.h>
#include <hip/hip_bf16.h>
#include <math.h>

// Problem constants
#define B   64
#define S   256
#define DD  512
#define H   8
#define DH  64
#define BH  (B*H)   // 512

typedef short s16x8 __attribute__((ext_vector_type(8)));
typedef short s16x4 __attribute__((ext_vector_type(4)));
typedef float f32x4 __attribute__((ext_vector_type(4)));

typedef __attribute__((address_space(3))) unsigned int       lds_u32;
typedef __attribute__((address_space(1))) const unsigned int glb_u32;

// Native bf16 cast (RNE). Compiler fuses adjacent pairs into v_cvt_pk_bf16_f32.
__device__ __forceinline__ short f2bf(float f) {
    __bf16 h = (__bf16)f;
    union { __bf16 b; short s; } u; u.b = h;
    return u.s;
}

__device__ __forceinline__ void glds16(const void* g, void* l) {
    __builtin_amdgcn_global_load_lds((glb_u32*)g, (lds_u32*)l, 16, 0, 0);
}

// ---------------------------------------------------------------------------
// PREP (merged): blockIdx ranges
//   [0, 4096)          : x f32 -> bf16
//   [4096, 5120)       : weight transpose wt[z][n][k] = w_z[k][n]
//   [5120, 5280)       : Toeplitz btf (fragment-linear)
//   [5280, 21664)      : pairwise MLP -> mfrag (fragment-linear)
// ---------------------------------------------------------------------------
__global__ __launch_bounds__(256) void prep_kernel(
    const float* __restrict__ x, ushort* __restrict__ xbf,
    const float* __restrict__ wq, const float* __restrict__ wk,
    const float* __restrict__ wv, const float* __restrict__ wd,
    ushort* __restrict__ wt,
    const float* __restrict__ c1k, const float* __restrict__ c3k,
    const float* __restrict__ c5k, ushort* __restrict__ btf,
    const float* __restrict__ particles,
    const float* __restrict__ mw1, const float* __restrict__ mb1,
    const float* __restrict__ mw2, const float* __restrict__ mb2,
    const float* __restrict__ mw3, const float* __restrict__ mb3,
    const float* __restrict__ c1b, const float* __restrict__ c3b,
    const float* __restrict__ c5b,
    float* __restrict__ mfrag)
{
    __shared__ float tile[32][33];
    __shared__ float w1[32], b1[8], w2[64], b2[8], w3[8];
    __shared__ float b3s;

    const int blk = blockIdx.x;
    const int tid = threadIdx.x;

    if (blk < 4096) {
        const int idx = blk * 256 + tid;
        const float4 f0 = *(const float4*)(x + (size_t)idx * 8);
        const float4 f1 = *(const float4*)(x + (size_t)idx * 8 + 4);
        s16x8 o = { f2bf(f0.x), f2bf(f0.y), f2bf(f0.z), f2bf(f0.w),
                    f2bf(f1.x), f2bf(f1.y), f2bf(f1.z), f2bf(f1.w) };
        *(s16x8*)(xbf + (size_t)idx * 8) = o;
    } else if (blk < 5120) {
        const int rem = blk - 4096;
        const int z  = rem >> 8;
        const int k0 = ((rem >> 4) & 15) * 32;
        const int n0 = (rem & 15) * 32;
        const float* w = (z == 0) ? wq : (z == 1) ? wk : (z == 2) ? wv : wd;
        const int tx = tid & 31, ty = tid >> 5;
        #pragma unroll
        for (int r = 0; r < 32; r += 8)
            tile[ty + r][tx] = w[(size_t)(k0 + ty + r) * DD + n0 + tx];
        __syncthreads();
        #pragma unroll
        for (int r = 0; r < 32; r += 8)
            wt[(size_t)z * DD * DD + (size_t)(n0 + ty + r) * DD + k0 + tx] =
                (ushort)f2bf(tile[tx][ty + r]);
    } else if (blk < 5280) {
        const int idx  = (blk - 5120) * 256 + tid;   // 0..40959
        const int lane = idx & 63;
        const int st   = (idx >> 6) % 40;
        const int n    = idx / (40 * 64);
        const int c    = n * 16 + (lane & 15);
        const int r    = st >> 3;
        const int tb   = (st & 7) * 32 + (lane >> 4) * 8;
        s16x8 o;
        #pragma unroll
        for (int e = 0; e < 8; ++e) {
            const int ki = tb + e - c + 127;
            float val = 0.f;
            if (ki >= 0 && ki < 256) {
                val = c5k[r * 256 + ki];
                if (r >= 1 && r <= 3) val += c3k[(r - 1) * 256 + ki];
                if (r == 2)           val += c1k[ki];
                val *= (1.f / 24.f);
            }
            o[e] = f2bf(val);
        }
        *(s16x8*)(btf + (size_t)idx * 8) = o;
    } else {
        if (tid < 32)                 w1[tid]        = mw1[tid];
        if (tid >= 32 && tid < 40)    b1[tid - 32]   = mb1[tid - 32];
        if (tid >= 64 && tid < 128)   w2[tid - 64]   = mw2[tid - 64];
        if (tid >= 128 && tid < 136)  b2[tid - 128]  = mb2[tid - 128];
        if (tid >= 136 && tid < 144)  w3[tid - 136]  = mw3[tid - 136];
        if (tid == 144)               b3s            = mb3[0];

        const int bi = blk - 5280;            // b*S + i
        const int bb = bi >> 8;
        const float pt_i  = particles[(size_t)bi * 3 + 0];
        const float eta_i = particles[(size_t)bi * 3 + 1];
        const float phi_i = particles[(size_t)bi * 3 + 2];

        const int j = tid;
        const float* pj = particles + ((size_t)(bb * S) + j) * 3;
        const float pt_j = pj[0], eta_j = pj[1], phi_j = pj[2];

        __syncthreads();

        const float d_eta = eta_i - eta_j;
        const float dp    = phi_i - phi_j;
        const float d_phi = dp - 6.28318530717958647692f
                                 * rintf(dp * 0.15915494309189533577f);
        const float delta = sqrtf(d_eta * d_eta + d_phi * d_phi);
        const float min_pt = fminf(pt_i, pt_j);
        const float kT = min_pt * delta;
        const float zf = min_pt / (pt_i + pt_j + 1e-8f);
        const float cd = cosf(d_phi);
        const float m2 = fmaxf(pt_i * pt_i + pt_j * pt_j - 2.0f * pt_i * pt_j * cd, 1e-8f);

        const float eps = 1e-8f;
        const float f[4] = { logf(fmaxf(delta, eps)),
                             logf(fmaxf(kT,    eps)),
                             logf(fmaxf(zf,    eps)),
                             logf(m2) };

        float h1[8];
        #pragma unroll
        for (int o = 0; o < 8; ++o) {
            float s = b1[o];
            #pragma unroll
            for (int i4 = 0; i4 < 4; ++i4) s += f[i4] * w1[i4 * 8 + o];
            h1[o] = fmaxf(s, 0.0f);
        }
        float h2[8];
        #pragma unroll
        for (int o = 0; o < 8; ++o) {
            float s = b2[o];
            #pragma unroll
            for (int i8 = 0; i8 < 8; ++i8) s += h1[i8] * w2[i8 * 8 + o];
            h2[o] = fmaxf(s, 0.0f);
        }
        float mv = b3s;
        #pragma unroll
        for (int i8 = 0; i8 < 8; ++i8) mv += h2[i8] * w3[i8];
        mv = fminf(fmaxf(mv, -10.0f), 10.0f);
        mv += (c1b[0] + c3b[0] + c5b[0]) * (1.f / 3.f);   // fold conv bias

        const int ii     = bi & 255;
        const int chunk2 = ii >> 7;
        const int rem2   = ii & 127;
        const int wr     = rem2 >> 6, rt = (rem2 >> 4) & 3, l4h = (rem2 >> 2) & 3, rg = rem2 & 3;
        const int wc     = j >> 6,   n2 = (j >> 4) & 3,  l15 = j & 15;
        const int lane   = l4h * 16 + l15;
        const int w8     = wr * 4 + wc;
        mfrag[((((size_t)(bb * 2 + chunk2)) * 8 + w8) * 64 + lane) * 64
              + rt * 16 + n2 * 4 + rg] = mv;
    }
}

// ---------------------------------------------------------------------------
// P3: merged Q/K/V GEMM, one launch, grid (128 tok-tiles, 4 feat-tiles, 3).
// z<2 (Q/K): A = W^T (features as m), B = tokens -> swapped epilogue.
// z=2 (V):   A = tokens (m), B = Wv^T -> direct vfrag epilogue.
// ---------------------------------------------------------------------------
__global__ __launch_bounds__(256) void gemm_qkv3_kernel(
    const ushort* __restrict__ wt, const ushort* __restrict__ xbf,
    ushort* __restrict__ qo, ushort* __restrict__ ko,
    ushort* __restrict__ vfrag)
{
    __shared__ ushort As[128 * 64];
    __shared__ ushort Bs[128 * 64];

    const int tid  = threadIdx.x;
    const int lane = tid & 63, w = tid >> 6;
    const int l15  = lane & 15, l4 = lane >> 4;
    const int wr   = w >> 1, wc = w & 1;
    const int bx = blockIdx.x, by = blockIdx.y, z = blockIdx.z;

    const ushort* srcA = (z < 2) ? wt + (size_t)z * DD * DD + (size_t)by * 128 * DD
                                 : xbf + (size_t)bx * 128 * DD;
    const ushort* srcB = (z < 2) ? xbf + (size_t)bx * 128 * DD
                                 : wt + (size_t)2 * DD * DD + (size_t)by * 128 * DD;

    f32x4 acc[4][4];
    #pragma unroll
    for (int mt = 0; mt < 4; ++mt)
        #pragma unroll
        for (int nt = 0; nt < 4; ++nt)
            acc[mt][nt] = (f32x4){0.f, 0.f, 0.f, 0.f};

    const int arow = tid >> 3;
    const int acol = (tid & 7) * 8;
    char* ldsA = (char*)As + (tid >> 6) * 1024;
    char* ldsB = (char*)Bs + (tid >> 6) * 1024;

    for (int k0 = 0; k0 < DD; k0 += 64) {
        #pragma unroll
        for (int i = 0; i < 4; ++i)
            glds16(srcA + (size_t)(arow + 32 * i) * DD + k0 + acol,
                   ldsA + 4096 * i);
        #pragma unroll
        for (int i = 0; i < 4; ++i)
            glds16(srcB + (size_t)(arow + 32 * i) * DD + k0 + acol,
                   ldsB + 4096 * i);
        __syncthreads();

        #pragma unroll
        for (int kk = 0; kk < 2; ++kk) {
            s16x8 af[4], bf[4];
            #pragma unroll
            for (int mt = 0; mt < 4; ++mt) {
                const int row = wr * 64 + mt * 16 + l15;
                af[mt] = *(const s16x8*)((char*)As + row * 128 + kk * 64 + l4 * 16);
            }
            #pragma unroll
            for (int nt = 0; nt < 4; ++nt) {
                const int col = wc * 64 + nt * 16 + l15;
                bf[nt] = *(const s16x8*)((char*)Bs + col * 128 + kk * 64 + l4 * 16);
            }
            #pragma unroll
            for (int mt = 0; mt < 4; ++mt)
                #pragma unroll
                for (int nt = 0; nt < 4; ++nt)
                    acc[mt][nt] = __builtin_amdgcn_mfma_f32_16x16x32_bf16(
                                      af[mt], bf[nt], acc[mt][nt], 0, 0, 0);
        }
        __syncthreads();
    }

    if (z < 2) {
        ushort* dst = (z == 0) ? qo : ko;
        #pragma unroll
        for (int mt = 0; mt < 4; ++mt)
            #pragma unroll
            for (int nt = 0; nt < 4; ++nt) {
                const int r = bx * 128 + wc * 64 + nt * 16 + l15;      // token
                const int c = by * 128 + wr * 64 + mt * 16 + l4 * 4;   // feature
                const int bb = r >> 8, ss = r & 255;
                const int hh = c >> 6, dd = c & 63;
                s16x4 pk = { f2bf(acc[mt][nt][0]), f2bf(acc[mt][nt][1]),
                             f2bf(acc[mt][nt][2]), f2bf(acc[mt][nt][3]) };
                *(s16x4*)(dst + (((size_t)(bb * H + hh)) * S + ss) * DH + dd) = pk;
            }
    } else {
        #pragma unroll
        for (int mt = 0; mt < 4; ++mt)
            #pragma unroll
            for (int nt = 0; nt < 4; ++nt) {
                const int r = bx * 128 + wr * 64 + mt * 16 + l4 * 4;   // token base
                const int c = by * 128 + wc * 64 + nt * 16 + l15;      // feature
                const int bb = r >> 8, ss = r & 255;
                const int hh = c >> 6;
                const int head = bb * H + hh;
                const int n  = (c >> 4) & 3;
                const int kk = ss >> 5;
                const int lanep = l15 + 16 * ((ss >> 3) & 3);
                const int e0 = ss & 7;
                s16x4 pk = { f2bf(acc[mt][nt][0]), f2bf(acc[mt][nt][1]),
                             f2bf(acc[mt][nt][2]), f2bf(acc[mt][nt][3]) };
                *(s16x4*)(vfrag + ((((size_t)(head * 4 + n)) * 8 + kk) * 64 + lanep) * 8 + e0) = pk;
            }
    }
}

// ---------------------------------------------------------------------------
// P3b: dense GEMM (swapped: A = dense_w^T, B = attn tokens), float4 + bias.
// ---------------------------------------------------------------------------
__global__ __launch_bounds__(256) void gemm_dense_kernel(
    const ushort* __restrict__ Wt, const ushort* __restrict__ Tok,
    const float* __restrict__ bias, float* __restrict__ outf)
{
    __shared__ ushort As[128 * 64];
    __shared__ ushort Bs[128 * 64];

    const int tid  = threadIdx.x;
    const int lane = tid & 63, w = tid >> 6;
    const int l15  = lane & 15, l4 = lane >> 4;
    const int wr   = w >> 1, wc = w & 1;
    const int frow0 = blockIdx.y * 128;
    const int trow0 = blockIdx.x * 128;

    f32x4 acc[4][4];
    #pragma unroll
    for (int mt = 0; mt < 4; ++mt)
        #pragma unroll
        for (int nt = 0; nt < 4; ++nt)
            acc[mt][nt] = (f32x4){0.f, 0.f, 0.f, 0.f};

    const int arow = tid >> 3;
    const int acol = (tid & 7) * 8;
    char* ldsA = (char*)As + (tid >> 6) * 1024;
    char* ldsB = (char*)Bs + (tid >> 6) * 1024;

    for (int k0 = 0; k0 < DD; k0 += 64) {
        #pragma unroll
        for (int i = 0; i < 4; ++i)
            glds16(Wt  + (size_t)(frow0 + arow + 32 * i) * DD + k0 + acol,
                   ldsA + 4096 * i);
        #pragma unroll
        for (int i = 0; i < 4; ++i)
            glds16(Tok + (size_t)(trow0 + arow + 32 * i) * DD + k0 + acol,
                   ldsB + 4096 * i);
        __syncthreads();

        #pragma unroll
        for (int kk = 0; kk < 2; ++kk) {
            s16x8 af[4], bf[4];
            #pragma unroll
            for (int mt = 0; mt < 4; ++mt) {
                const int row = wr * 64 + mt * 16 + l15;
                af[mt] = *(const s16x8*)((char*)As + row * 128 + kk * 64 + l4 * 16);
            }
            #pragma unroll
            for (int nt = 0; nt < 4; ++nt) {
                const int col = wc * 64 + nt * 16 + l15;
                bf[nt] = *(const s16x8*)((char*)Bs + col * 128 + kk * 64 + l4 * 16);
            }
            #pragma unroll
            for (int mt = 0; mt < 4; ++mt)
                #pragma unroll
                for (int nt = 0; nt < 4; ++nt)
                    acc[mt][nt] = __builtin_amdgcn_mfma_f32_16x16x32_bf16(
                                      af[mt], bf[nt], acc[mt][nt], 0, 0, 0);
        }
        __syncthreads();
    }

    #pragma unroll
    for (int mt = 0; mt < 4; ++mt) {
        const int c = frow0 + wr * 64 + mt * 16 + l4 * 4;
        const float4 b4 = *(const float4*)(bias + c);
        #pragma unroll
        for (int nt = 0; nt < 4; ++nt) {
            const int r = trow0 + wc * 64 + nt * 16 + l15;
            float4 o = make_float4(acc[mt][nt][0] + b4.x, acc[mt][nt][1] + b4.y,
                                   acc[mt][nt][2] + b4.z, acc[mt][nt][3] + b4.w);
            *(float4*)(outf + (size_t)r * DD + c) = o;
        }
    }
}

// ---------------------------------------------------------------------------
// K3: MFMA-fused  scores -> Toeplitz conv -> +m -> softmax(1 barrier) -> PV
// LB(512,2): occupancy is LDS-capped at 2 blocks/CU anyway (77824B x 2),
// so relaxing min-waves doubles the VGPR budget to 256 -- the 4-slot
// literal prefetch now fits in registers (r16's spill was the LB(512,4)
// 128-VGPR cap, not the prefetch itself).
// LDS: SC [144][512B] + RED2 [128][4][2] = 77824 B.
// ---------------------------------------------------------------------------
__global__ __launch_bounds__(512, 2) void fused_mfma_kernel(
    const ushort* __restrict__ q, const ushort* __restrict__ kbuf,
    const ushort* __restrict__ vfrag, const ushort* __restrict__ btf,
    const float* __restrict__ mfrag, ushort* __restrict__ attn)
{
    __shared__ __align__(16) char pool[77824];
    char* SC    = pool;                     // scores bf16 [144][512B], swizzled
    char* PB    = pool;                     // P bf16 [128][512B] (aliases SC)
    float* RED2 = (float*)(pool + 73728);   // [128 rows][4 wc][2] = 4 KB

    const int tid  = threadIdx.x;
    const int lane = tid & 63;
    const int w    = tid >> 6;              // 0..7
    const int wr   = w >> 2, wc = w & 3;
    const int l15  = lane & 15, l4 = lane >> 4;
    const int head = blockIdx.y;            // b*H + h
    const int bb   = head >> 3, hh = head & 7;
    const int i0   = blockIdx.x * 128;
    const int cb   = wc * 64;               // this wave's column strip

    // ---- phase 1 (swapped): S = K(A) x Q(B); C: m=t, n=i ----
    {
        const ushort* kb_h = kbuf + (size_t)head * S * DH;
        const ushort* qb_h = q    + (size_t)head * S * DH;
        const int ntiles = 5 - wr;          // 5 or 4
        const int tg0    = wr * 5;
        f32x4 sacc[4][5];
        #pragma unroll
        for (int mt = 0; mt < 4; ++mt)
            #pragma unroll
            for (int nt = 0; nt < 5; ++nt)
                sacc[mt][nt] = (f32x4){0.f, 0.f, 0.f, 0.f};

        #pragma unroll
        for (int kk = 0; kk < 2; ++kk) {
            s16x8 afr[4];
            #pragma unroll
            for (int mt = 0; mt < 4; ++mt)
                afr[mt] = *(const s16x8*)(kb_h
                          + (size_t)(cb + mt * 16 + l15) * 64 + kk * 32 + 8 * l4);
            #pragma unroll
            for (int nt = 0; nt < 5; ++nt) {
                if (nt < ntiles) {
                    const int qrow = i0 - 8 + (tg0 + nt) * 16 + l15;
                    s16x8 bfr = (s16x8){0,0,0,0,0,0,0,0};
                    if ((unsigned)qrow < (unsigned)S)
                        bfr = *(const s16x8*)(qb_h + (size_t)qrow * 64 + kk * 32 + 8 * l4);
                    #pragma unroll
                    for (int mt = 0; mt < 4; ++mt)
                        sacc[mt][nt] = __builtin_amdgcn_mfma_f32_16x16x32_bf16(
                                           afr[mt], bfr, sacc[mt][nt], 0, 0, 0);
                }
            }
        }
        #pragma unroll
        for (int mt = 0; mt < 4; ++mt)
            #pragma unroll
            for (int nt = 0; nt < 5; ++nt) {
                if (nt < ntiles) {
                    const int row = (tg0 + nt) * 16 + l15;   // SC row 0..143
                    const int t0  = cb + mt * 16 + l4 * 4;
                    s16x4 pk = { f2bf(sacc[mt][nt][0]), f2bf(sacc[mt][nt][1]),
                                 f2bf(sacc[mt][nt][2]), f2bf(sacc[mt][nt][3]) };
                    const int byt = (row * 512 + t0 * 2) ^ ((row & 7) << 4);
                    *(s16x4*)(SC + byt) = pk;
                }
            }
    }
    __syncthreads();

    // ---- phase 2: Toeplitz conv; 4-slot literal prefetch (depth ~2 steps) ----
    f32x4 cacc[4][4];
    #pragma unroll
    for (int rt = 0; rt < 4; ++rt)
        #pragma unroll
        for (int n = 0; n < 4; ++n)
            cacc[rt][n] = (f32x4){0.f, 0.f, 0.f, 0.f};

    {
        const ushort* btw = btf + (size_t)(wc * 4) * 40 * 512 + lane * 8;

        s16x8 pb[4][4];
        auto ldB = [&](int st, int slot) {
            #pragma unroll
            for (int i = 0; i < 4; ++i)
                pb[slot][i] = *(const s16x8*)(btw + (size_t)(i * 40 + st) * 512);
        };
        auto convStep = [&](int st, int slot) {
            const int r = st >> 3, kb2 = (st & 7) * 64 + 16 * l4;
            __builtin_amdgcn_s_setprio(1);
            #pragma unroll
            for (int rt = 0; rt < 4; ++rt) {
                const int sr = wr * 64 + rt * 16 + l15 + r + 6;   // <= 137
                const s16x8 afr = *(const s16x8*)(SC + ((sr * 512 + kb2) ^ ((sr & 7) << 4)));
                #pragma unroll
                for (int n = 0; n < 4; ++n)
                    cacc[rt][n] = __builtin_amdgcn_mfma_f32_16x16x32_bf16(
                                      afr, pb[slot][n], cacc[rt][n], 0, 0, 0);
            }
            __builtin_amdgcn_s_setprio(0);
        };

        ldB(0, 0); ldB(1, 1);
        for (int qq = 0; qq < 10; ++qq) {       // literal slots only (rule #20)
            const int st = qq * 4;
            ldB(st + 2, 2);
            convStep(st + 0, 0);
            ldB(st + 3, 3);
            convStep(st + 1, 1);
            if (st + 4 < 40) ldB(st + 4, 0);
            convStep(st + 2, 2);
            if (st + 5 < 40) ldB(st + 5, 1);
            convStep(st + 3, 3);
        }
    }

    // ---- phase 2.5: + m (fragment-linear, consume each float4 immediately) ----
    {
        const float* mf = mfrag
            + ((((size_t)(bb * 2 + blockIdx.x)) * 8 + w) * 64 + lane) * 64;
        #pragma unroll
        for (int rt = 0; rt < 4; ++rt)
            #pragma unroll
            for (int n = 0; n < 4; ++n) {
                const float4 mv = *(const float4*)(mf + rt * 16 + n * 4);
                cacc[rt][n][0] += mv.x;
                cacc[rt][n][1] += mv.y;
                cacc[rt][n][2] += mv.z;
                cacc[rt][n][3] += mv.w;
            }
    }

    // ---- phase 3: single-barrier softmax (true wave max + (M,S) exchange) ----
    float wM[4][4];
    #pragma unroll
    for (int rt = 0; rt < 4; ++rt)
        #pragma unroll
        for (int rg = 0; rg < 4; ++rg) {
            float mx = fmaxf(fmaxf(cacc[rt][0][rg], cacc[rt][1][rg]),
                             fmaxf(cacc[rt][2][rg], cacc[rt][3][rg]));
            mx = fmaxf(mx, __shfl_xor(mx, 1));
            mx = fmaxf(mx, __shfl_xor(mx, 2));
            mx = fmaxf(mx, __shfl_xor(mx, 4));
            mx = fmaxf(mx, __shfl_xor(mx, 8));
            wM[rt][rg] = mx;
        }
    #pragma unroll
    for (int rt = 0; rt < 4; ++rt)
        #pragma unroll
        for (int n = 0; n < 4; ++n) {
            cacc[rt][n][0] = __expf(cacc[rt][n][0] - wM[rt][0]);
            cacc[rt][n][1] = __expf(cacc[rt][n][1] - wM[rt][1]);
            cacc[rt][n][2] = __expf(cacc[rt][n][2] - wM[rt][2]);
            cacc[rt][n][3] = __expf(cacc[rt][n][3] - wM[rt][3]);
        }
    #pragma unroll
    for (int rt = 0; rt < 4; ++rt)
        #pragma unroll
        for (int rg = 0; rg < 4; ++rg) {
            float s = cacc[rt][0][rg] + cacc[rt][1][rg]
                    + cacc[rt][2][rg] + cacc[rt][3][rg];
            s += __shfl_xor(s, 1);
            s += __shfl_xor(s, 2);
            s += __shfl_xor(s, 4);
            s += __shfl_xor(s, 8);
            if (l15 == 0) {
                const int row = wr * 64 + rt * 16 + l4 * 4 + rg;
                RED2[row * 8 + wc * 2 + 0] = wM[rt][rg];
                RED2[row * 8 + wc * 2 + 1] = s;
            }
        }
    __syncthreads();   // also guarantees all conv SC reads done (pre-PB write)

    // ---- combine + write P (bf16, swizzled, aliases SC rows 0..127) ----
    #pragma unroll
    for (int rt = 0; rt < 4; ++rt)
        #pragma unroll
        for (int rg = 0; rg < 4; ++rg) {
            const int row = wr * 64 + rt * 16 + l4 * 4 + rg;
            const float2 p0 = *(const float2*)&RED2[row * 8 + 0];
            const float2 p1 = *(const float2*)&RED2[row * 8 + 2];
            const float2 p2 = *(const float2*)&RED2[row * 8 + 4];
            const float2 p3 = *(const float2*)&RED2[row * 8 + 6];
            const float gM = fmaxf(fmaxf(p0.x, p1.x), fmaxf(p2.x, p3.x));
            const float tot = p0.y * __expf(p0.x - gM) + p1.y * __expf(p1.x - gM)
                            + p2.y * __expf(p2.x - gM) + p3.y * __expf(p3.x - gM);
            const float fac = __expf(wM[rt][rg] - gM) / tot;
            #pragma unroll
            for (int n = 0; n < 4; ++n) {
                const int col = cb + n * 16 + l15;
                const int byt = (row * 512 + col * 2) ^ ((row & 7) << 4);
                *(short*)(PB + byt) = f2bf(cacc[rt][n][rg] * fac);
            }
        }
    __syncthreads();

    // ---- phase 4: PV via MFMA; wave w -> rows w*16..w*16+15 ----
    const ushort* vf_h = vfrag + (size_t)head * 4 * 8 * 512 + lane * 8;
    f32x4 pacc[4];
    #pragma unroll
    for (int n = 0; n < 4; ++n) pacc[n] = (f32x4){0.f, 0.f, 0.f, 0.f};
    #pragma unroll
    for (int kk = 0; kk < 8; ++kk) {
        const int prow = w * 16 + l15;      // 0..127
        const int byta = (prow * 512 + kk * 64 + 16 * l4) ^ ((prow & 7) << 4);
        const s16x8 pa = *(const s16x8*)(PB + byta);
        #pragma unroll
        for (int n = 0; n < 4; ++n) {
            const s16x8 vb8 = *(const s16x8*)(vf_h + (size_t)(n * 8 + kk) * 512);
            pacc[n] = __builtin_amdgcn_mfma_f32_16x16x32_bf16(pa, vb8, pacc[n], 0, 0, 0);
        }
    }
    #pragma unroll
    for (int n = 0; n < 4; ++n)
        #pragma unroll
        for (int rg = 0; rg < 4; ++rg) {
            const int i = i0 + w * 16 + l4 * 4 + rg;
            const int d = n * 16 + l15;
            attn[(((size_t)bb * S + i) * H + hh) * DH + d] = (ushort)f2bf(pacc[n][rg]);
        }
}

// ---------------------------------------------------------------------------
// launcher (4 kernels)
// ---------------------------------------------------------------------------
extern "C" void kernel_launch(void* const* d_in, const int* in_sizes, int n_in,
                              void* d_out, int out_size, void* d_ws, size_t ws_size,
                              hipStream_t stream)
{
    (void)in_sizes; (void)n_in; (void)out_size; (void)ws_size;

    const float* x        = (const float*)d_in[0];
    const float* particles= (const float*)d_in[1];
    const float* wq       = (const float*)d_in[2];
    const float* wk       = (const float*)d_in[3];
    const float* wv       = (const float*)d_in[4];
    const float* dense_w  = (const float*)d_in[5];
    const float* dense_b  = (const float*)d_in[6];
    const float* c1k      = (const float*)d_in[7];
    const float* c1b      = (const float*)d_in[8];
    const float* c3k      = (const float*)d_in[9];
    const float* c3b      = (const float*)d_in[10];
    const float* c5k      = (const float*)d_in[11];
    const float* c5b      = (const float*)d_in[12];
    const float* mw1      = (const float*)d_in[13];
    const float* mb1      = (const float*)d_in[14];
    const float* mw2      = (const float*)d_in[15];
    const float* mb2      = (const float*)d_in[16];
    const float* mw3      = (const float*)d_in[17];
    const float* mb3      = (const float*)d_in[18];
    float* out = (float*)d_out;

    // workspace layout (ushort units unless noted), total ~104 MB
    ushort* xbf   = (ushort*)d_ws;                       //  8,388,608
    ushort* wt    = xbf   + (size_t)8388608;             //  1,048,576
    ushort* qb    = wt    + (size_t)1048576;             //  8,388,608
    ushort* kb    = qb    + (size_t)8388608;             //  8,388,608
    ushort* attnb = kb    + (size_t)8388608;             //  8,388,608
    ushort* btf   = attnb + (size_t)8388608;             //    327,680  frag-linear
    ushort* vfrag = btf   + (size_t)327680;              //  8,388,608  frag-linear
    float*  mfrag = (float*)(vfrag + (size_t)8388608);   //  4,194,304 f32 frag-linear

    prep_kernel<<<dim3(21664), 256, 0, stream>>>(
        x, xbf, wq, wk, wv, dense_w, wt,
        c1k, c3k, c5k, btf,
        particles, mw1, mb1, mw2, mb2, mw3, mb3, c1b, c3b, c5b, mfrag);

    gemm_qkv3_kernel<<<dim3(128, 4, 3), 256, 0, stream>>>(
        wt, xbf, qb, kb, vfrag);

    fused_mfma_kernel<<<dim3(2, BH), 512, 0, stream>>>(
        qb, kb, vfrag, btf, mfrag, attnb);

    gemm_dense_kernel<<<dim3(128, 4), 256, 0, stream>>>(
        wt + (size_t)3 * DD * DD, attnb, dense_b, out);
}

// Round 19
// 230.690 us; speedup vs baseline: 1.0849x; 1.0849x over previous
//
#include <hip/hip_runtime.h>
#include <hip/hip_bf16.h>
#include <math.h>

// Problem constants
#define B   64
#define S   256
#define DD  512
#define H   8
#define DH  64
#define BH  (B*H)   // 512

typedef short s16x8 __attribute__((ext_vector_type(8)));
typedef short s16x4 __attribute__((ext_vector_type(4)));
typedef float f32x4 __attribute__((ext_vector_type(4)));

typedef __attribute__((address_space(3))) unsigned int       lds_u32;
typedef __attribute__((address_space(1))) const unsigned int glb_u32;

// Native bf16 cast (RNE). Compiler fuses adjacent pairs into v_cvt_pk_bf16_f32.
__device__ __forceinline__ short f2bf(float f) {
    __bf16 h = (__bf16)f;
    union { __bf16 b; short s; } u; u.b = h;
    return u.s;
}

__device__ __forceinline__ void glds16(const void* g, void* l) {
    __builtin_amdgcn_global_load_lds((glb_u32*)g, (lds_u32*)l, 16, 0, 0);
}

// ---------------------------------------------------------------------------
// PREP (merged): blockIdx ranges
//   [0, 4096)          : x f32 -> bf16
//   [4096, 5120)       : weight transpose wt[z][n][k] = w_z[k][n]
//   [5120, 5280)       : Toeplitz btf (fragment-linear)
//   [5280, 21664)      : pairwise MLP -> mfrag (fragment-linear)
// ---------------------------------------------------------------------------
__global__ __launch_bounds__(256) void prep_kernel(
    const float* __restrict__ x, ushort* __restrict__ xbf,
    const float* __restrict__ wq, const float* __restrict__ wk,
    const float* __restrict__ wv, const float* __restrict__ wd,
    ushort* __restrict__ wt,
    const float* __restrict__ c1k, const float* __restrict__ c3k,
    const float* __restrict__ c5k, ushort* __restrict__ btf,
    const float* __restrict__ particles,
    const float* __restrict__ mw1, const float* __restrict__ mb1,
    const float* __restrict__ mw2, const float* __restrict__ mb2,
    const float* __restrict__ mw3, const float* __restrict__ mb3,
    const float* __restrict__ c1b, const float* __restrict__ c3b,
    const float* __restrict__ c5b,
    float* __restrict__ mfrag)
{
    __shared__ float tile[32][33];
    __shared__ float w1[32], b1[8], w2[64], b2[8], w3[8];
    __shared__ float b3s;

    const int blk = blockIdx.x;
    const int tid = threadIdx.x;

    if (blk < 4096) {
        const int idx = blk * 256 + tid;
        const float4 f0 = *(const float4*)(x + (size_t)idx * 8);
        const float4 f1 = *(const float4*)(x + (size_t)idx * 8 + 4);
        s16x8 o = { f2bf(f0.x), f2bf(f0.y), f2bf(f0.z), f2bf(f0.w),
                    f2bf(f1.x), f2bf(f1.y), f2bf(f1.z), f2bf(f1.w) };
        *(s16x8*)(xbf + (size_t)idx * 8) = o;
    } else if (blk < 5120) {
        const int rem = blk - 4096;
        const int z  = rem >> 8;
        const int k0 = ((rem >> 4) & 15) * 32;
        const int n0 = (rem & 15) * 32;
        const float* w = (z == 0) ? wq : (z == 1) ? wk : (z == 2) ? wv : wd;
        const int tx = tid & 31, ty = tid >> 5;
        #pragma unroll
        for (int r = 0; r < 32; r += 8)
            tile[ty + r][tx] = w[(size_t)(k0 + ty + r) * DD + n0 + tx];
        __syncthreads();
        #pragma unroll
        for (int r = 0; r < 32; r += 8)
            wt[(size_t)z * DD * DD + (size_t)(n0 + ty + r) * DD + k0 + tx] =
                (ushort)f2bf(tile[tx][ty + r]);
    } else if (blk < 5280) {
        const int idx  = (blk - 5120) * 256 + tid;   // 0..40959
        const int lane = idx & 63;
        const int st   = (idx >> 6) % 40;
        const int n    = idx / (40 * 64);
        const int c    = n * 16 + (lane & 15);
        const int r    = st >> 3;
        const int tb   = (st & 7) * 32 + (lane >> 4) * 8;
        s16x8 o;
        #pragma unroll
        for (int e = 0; e < 8; ++e) {
            const int ki = tb + e - c + 127;
            float val = 0.f;
            if (ki >= 0 && ki < 256) {
                val = c5k[r * 256 + ki];
                if (r >= 1 && r <= 3) val += c3k[(r - 1) * 256 + ki];
                if (r == 2)           val += c1k[ki];
                val *= (1.f / 24.f);
            }
            o[e] = f2bf(val);
        }
        *(s16x8*)(btf + (size_t)idx * 8) = o;
    } else {
        if (tid < 32)                 w1[tid]        = mw1[tid];
        if (tid >= 32 && tid < 40)    b1[tid - 32]   = mb1[tid - 32];
        if (tid >= 64 && tid < 128)   w2[tid - 64]   = mw2[tid - 64];
        if (tid >= 128 && tid < 136)  b2[tid - 128]  = mb2[tid - 128];
        if (tid >= 136 && tid < 144)  w3[tid - 136]  = mw3[tid - 136];
        if (tid == 144)               b3s            = mb3[0];

        const int bi = blk - 5280;            // b*S + i
        const int bb = bi >> 8;
        const float pt_i  = particles[(size_t)bi * 3 + 0];
        const float eta_i = particles[(size_t)bi * 3 + 1];
        const float phi_i = particles[(size_t)bi * 3 + 2];

        const int j = tid;
        const float* pj = particles + ((size_t)(bb * S) + j) * 3;
        const float pt_j = pj[0], eta_j = pj[1], phi_j = pj[2];

        __syncthreads();

        const float d_eta = eta_i - eta_j;
        const float dp    = phi_i - phi_j;
        const float d_phi = dp - 6.28318530717958647692f
                                 * rintf(dp * 0.15915494309189533577f);
        const float delta = sqrtf(d_eta * d_eta + d_phi * d_phi);
        const float min_pt = fminf(pt_i, pt_j);
        const float kT = min_pt * delta;
        const float zf = min_pt / (pt_i + pt_j + 1e-8f);
        const float cd = cosf(d_phi);
        const float m2 = fmaxf(pt_i * pt_i + pt_j * pt_j - 2.0f * pt_i * pt_j * cd, 1e-8f);

        const float eps = 1e-8f;
        const float f[4] = { logf(fmaxf(delta, eps)),
                             logf(fmaxf(kT,    eps)),
                             logf(fmaxf(zf,    eps)),
                             logf(m2) };

        float h1[8];
        #pragma unroll
        for (int o = 0; o < 8; ++o) {
            float s = b1[o];
            #pragma unroll
            for (int i4 = 0; i4 < 4; ++i4) s += f[i4] * w1[i4 * 8 + o];
            h1[o] = fmaxf(s, 0.0f);
        }
        float h2[8];
        #pragma unroll
        for (int o = 0; o < 8; ++o) {
            float s = b2[o];
            #pragma unroll
            for (int i8 = 0; i8 < 8; ++i8) s += h1[i8] * w2[i8 * 8 + o];
            h2[o] = fmaxf(s, 0.0f);
        }
        float mv = b3s;
        #pragma unroll
        for (int i8 = 0; i8 < 8; ++i8) mv += h2[i8] * w3[i8];
        mv = fminf(fmaxf(mv, -10.0f), 10.0f);
        mv += (c1b[0] + c3b[0] + c5b[0]) * (1.f / 3.f);   // fold conv bias

        const int ii     = bi & 255;
        const int chunk2 = ii >> 7;
        const int rem2   = ii & 127;
        const int wr     = rem2 >> 6, rt = (rem2 >> 4) & 3, l4h = (rem2 >> 2) & 3, rg = rem2 & 3;
        const int wc     = j >> 6,   n2 = (j >> 4) & 3,  l15 = j & 15;
        const int lane   = l4h * 16 + l15;
        const int w8     = wr * 4 + wc;
        mfrag[((((size_t)(bb * 2 + chunk2)) * 8 + w8) * 64 + lane) * 64
              + rt * 16 + n2 * 4 + rg] = mv;
    }
}

// ---------------------------------------------------------------------------
// P3: merged Q/K/V GEMM, one launch, grid (128 tok-tiles, 4 feat-tiles, 3).
// z<2 (Q/K): A = W^T (features as m), B = tokens -> swapped epilogue.
// z=2 (V):   A = tokens (m), B = Wv^T -> direct vfrag epilogue.
// ---------------------------------------------------------------------------
__global__ __launch_bounds__(256) void gemm_qkv3_kernel(
    const ushort* __restrict__ wt, const ushort* __restrict__ xbf,
    ushort* __restrict__ qo, ushort* __restrict__ ko,
    ushort* __restrict__ vfrag)
{
    __shared__ ushort As[128 * 64];
    __shared__ ushort Bs[128 * 64];

    const int tid  = threadIdx.x;
    const int lane = tid & 63, w = tid >> 6;
    const int l15  = lane & 15, l4 = lane >> 4;
    const int wr   = w >> 1, wc = w & 1;
    const int bx = blockIdx.x, by = blockIdx.y, z = blockIdx.z;

    const ushort* srcA = (z < 2) ? wt + (size_t)z * DD * DD + (size_t)by * 128 * DD
                                 : xbf + (size_t)bx * 128 * DD;
    const ushort* srcB = (z < 2) ? xbf + (size_t)bx * 128 * DD
                                 : wt + (size_t)2 * DD * DD + (size_t)by * 128 * DD;

    f32x4 acc[4][4];
    #pragma unroll
    for (int mt = 0; mt < 4; ++mt)
        #pragma unroll
        for (int nt = 0; nt < 4; ++nt)
            acc[mt][nt] = (f32x4){0.f, 0.f, 0.f, 0.f};

    const int arow = tid >> 3;
    const int acol = (tid & 7) * 8;
    char* ldsA = (char*)As + (tid >> 6) * 1024;
    char* ldsB = (char*)Bs + (tid >> 6) * 1024;

    for (int k0 = 0; k0 < DD; k0 += 64) {
        #pragma unroll
        for (int i = 0; i < 4; ++i)
            glds16(srcA + (size_t)(arow + 32 * i) * DD + k0 + acol,
                   ldsA + 4096 * i);
        #pragma unroll
        for (int i = 0; i < 4; ++i)
            glds16(srcB + (size_t)(arow + 32 * i) * DD + k0 + acol,
                   ldsB + 4096 * i);
        __syncthreads();

        #pragma unroll
        for (int kk = 0; kk < 2; ++kk) {
            s16x8 af[4], bf[4];
            #pragma unroll
            for (int mt = 0; mt < 4; ++mt) {
                const int row = wr * 64 + mt * 16 + l15;
                af[mt] = *(const s16x8*)((char*)As + row * 128 + kk * 64 + l4 * 16);
            }
            #pragma unroll
            for (int nt = 0; nt < 4; ++nt) {
                const int col = wc * 64 + nt * 16 + l15;
                bf[nt] = *(const s16x8*)((char*)Bs + col * 128 + kk * 64 + l4 * 16);
            }
            #pragma unroll
            for (int mt = 0; mt < 4; ++mt)
                #pragma unroll
                for (int nt = 0; nt < 4; ++nt)
                    acc[mt][nt] = __builtin_amdgcn_mfma_f32_16x16x32_bf16(
                                      af[mt], bf[nt], acc[mt][nt], 0, 0, 0);
        }
        __syncthreads();
    }

    if (z < 2) {
        ushort* dst = (z == 0) ? qo : ko;
        #pragma unroll
        for (int mt = 0; mt < 4; ++mt)
            #pragma unroll
            for (int nt = 0; nt < 4; ++nt) {
                const int r = bx * 128 + wc * 64 + nt * 16 + l15;      // token
                const int c = by * 128 + wr * 64 + mt * 16 + l4 * 4;   // feature
                const int bb = r >> 8, ss = r & 255;
                const int hh = c >> 6, dd = c & 63;
                s16x4 pk = { f2bf(acc[mt][nt][0]), f2bf(acc[mt][nt][1]),
                             f2bf(acc[mt][nt][2]), f2bf(acc[mt][nt][3]) };
                *(s16x4*)(dst + (((size_t)(bb * H + hh)) * S + ss) * DH + dd) = pk;
            }
    } else {
        #pragma unroll
        for (int mt = 0; mt < 4; ++mt)
            #pragma unroll
            for (int nt = 0; nt < 4; ++nt) {
                const int r = bx * 128 + wr * 64 + mt * 16 + l4 * 4;   // token base
                const int c = by * 128 + wc * 64 + nt * 16 + l15;      // feature
                const int bb = r >> 8, ss = r & 255;
                const int hh = c >> 6;
                const int head = bb * H + hh;
                const int n  = (c >> 4) & 3;
                const int kk = ss >> 5;
                const int lanep = l15 + 16 * ((ss >> 3) & 3);
                const int e0 = ss & 7;
                s16x4 pk = { f2bf(acc[mt][nt][0]), f2bf(acc[mt][nt][1]),
                             f2bf(acc[mt][nt][2]), f2bf(acc[mt][nt][3]) };
                *(s16x4*)(vfrag + ((((size_t)(head * 4 + n)) * 8 + kk) * 64 + lanep) * 8 + e0) = pk;
            }
    }
}

// ---------------------------------------------------------------------------
// P3b: dense GEMM (swapped: A = dense_w^T, B = attn tokens), float4 + bias.
// ---------------------------------------------------------------------------
__global__ __launch_bounds__(256) void gemm_dense_kernel(
    const ushort* __restrict__ Wt, const ushort* __restrict__ Tok,
    const float* __restrict__ bias, float* __restrict__ outf)
{
    __shared__ ushort As[128 * 64];
    __shared__ ushort Bs[128 * 64];

    const int tid  = threadIdx.x;
    const int lane = tid & 63, w = tid >> 6;
    const int l15  = lane & 15, l4 = lane >> 4;
    const int wr   = w >> 1, wc = w & 1;
    const int frow0 = blockIdx.y * 128;
    const int trow0 = blockIdx.x * 128;

    f32x4 acc[4][4];
    #pragma unroll
    for (int mt = 0; mt < 4; ++mt)
        #pragma unroll
        for (int nt = 0; nt < 4; ++nt)
            acc[mt][nt] = (f32x4){0.f, 0.f, 0.f, 0.f};

    const int arow = tid >> 3;
    const int acol = (tid & 7) * 8;
    char* ldsA = (char*)As + (tid >> 6) * 1024;
    char* ldsB = (char*)Bs + (tid >> 6) * 1024;

    for (int k0 = 0; k0 < DD; k0 += 64) {
        #pragma unroll
        for (int i = 0; i < 4; ++i)
            glds16(Wt  + (size_t)(frow0 + arow + 32 * i) * DD + k0 + acol,
                   ldsA + 4096 * i);
        #pragma unroll
        for (int i = 0; i < 4; ++i)
            glds16(Tok + (size_t)(trow0 + arow + 32 * i) * DD + k0 + acol,
                   ldsB + 4096 * i);
        __syncthreads();

        #pragma unroll
        for (int kk = 0; kk < 2; ++kk) {
            s16x8 af[4], bf[4];
            #pragma unroll
            for (int mt = 0; mt < 4; ++mt) {
                const int row = wr * 64 + mt * 16 + l15;
                af[mt] = *(const s16x8*)((char*)As + row * 128 + kk * 64 + l4 * 16);
            }
            #pragma unroll
            for (int nt = 0; nt < 4; ++nt) {
                const int col = wc * 64 + nt * 16 + l15;
                bf[nt] = *(const s16x8*)((char*)Bs + col * 128 + kk * 64 + l4 * 16);
            }
            #pragma unroll
            for (int mt = 0; mt < 4; ++mt)
                #pragma unroll
                for (int nt = 0; nt < 4; ++nt)
                    acc[mt][nt] = __builtin_amdgcn_mfma_f32_16x16x32_bf16(
                                      af[mt], bf[nt], acc[mt][nt], 0, 0, 0);
        }
        __syncthreads();
    }

    #pragma unroll
    for (int mt = 0; mt < 4; ++mt) {
        const int c = frow0 + wr * 64 + mt * 16 + l4 * 4;
        const float4 b4 = *(const float4*)(bias + c);
        #pragma unroll
        for (int nt = 0; nt < 4; ++nt) {
            const int r = trow0 + wc * 64 + nt * 16 + l15;
            float4 o = make_float4(acc[mt][nt][0] + b4.x, acc[mt][nt][1] + b4.y,
                                   acc[mt][nt][2] + b4.z, acc[mt][nt][3] + b4.w);
            *(float4*)(outf + (size_t)r * DD + c) = o;
        }
    }
}

// ---------------------------------------------------------------------------
// K3: MFMA-fused  scores -> Toeplitz conv -> +m -> softmax(1 barrier) -> PV
// r17/r15 kernel VERBATIM. 2-slot literal prefetch + setprio, LB(512,4).
// Both deeper-prefetch variants are measured dead ends:
//   r16 4-slot @ LB(512,4): scratch spill (128-VGPR cap);
//   r18 4-slot @ LB(512,2): unified VGPR+AGPR > 128/wave -> 1 block/CU,
//   occupancy 43->23%, fused 140->172.
// LDS: SC [144][512B] + RED2 [128][4][2] = 77824 B (2 blocks/CU).
// ---------------------------------------------------------------------------
__global__ __launch_bounds__(512, 4) void fused_mfma_kernel(
    const ushort* __restrict__ q, const ushort* __restrict__ kbuf,
    const ushort* __restrict__ vfrag, const ushort* __restrict__ btf,
    const float* __restrict__ mfrag, ushort* __restrict__ attn)
{
    __shared__ __align__(16) char pool[77824];
    char* SC    = pool;                     // scores bf16 [144][512B], swizzled
    char* PB    = pool;                     // P bf16 [128][512B] (aliases SC)
    float* RED2 = (float*)(pool + 73728);   // [128 rows][4 wc][2] = 4 KB

    const int tid  = threadIdx.x;
    const int lane = tid & 63;
    const int w    = tid >> 6;              // 0..7
    const int wr   = w >> 2, wc = w & 3;
    const int l15  = lane & 15, l4 = lane >> 4;
    const int head = blockIdx.y;            // b*H + h
    const int bb   = head >> 3, hh = head & 7;
    const int i0   = blockIdx.x * 128;
    const int cb   = wc * 64;               // this wave's column strip

    // ---- phase 1 (swapped): S = K(A) x Q(B); C: m=t, n=i ----
    {
        const ushort* kb_h = kbuf + (size_t)head * S * DH;
        const ushort* qb_h = q    + (size_t)head * S * DH;
        const int ntiles = 5 - wr;          // 5 or 4
        const int tg0    = wr * 5;
        f32x4 sacc[4][5];
        #pragma unroll
        for (int mt = 0; mt < 4; ++mt)
            #pragma unroll
            for (int nt = 0; nt < 5; ++nt)
                sacc[mt][nt] = (f32x4){0.f, 0.f, 0.f, 0.f};

        #pragma unroll
        for (int kk = 0; kk < 2; ++kk) {
            s16x8 afr[4];
            #pragma unroll
            for (int mt = 0; mt < 4; ++mt)
                afr[mt] = *(const s16x8*)(kb_h
                          + (size_t)(cb + mt * 16 + l15) * 64 + kk * 32 + 8 * l4);
            #pragma unroll
            for (int nt = 0; nt < 5; ++nt) {
                if (nt < ntiles) {
                    const int qrow = i0 - 8 + (tg0 + nt) * 16 + l15;
                    s16x8 bfr = (s16x8){0,0,0,0,0,0,0,0};
                    if ((unsigned)qrow < (unsigned)S)
                        bfr = *(const s16x8*)(qb_h + (size_t)qrow * 64 + kk * 32 + 8 * l4);
                    #pragma unroll
                    for (int mt = 0; mt < 4; ++mt)
                        sacc[mt][nt] = __builtin_amdgcn_mfma_f32_16x16x32_bf16(
                                           afr[mt], bfr, sacc[mt][nt], 0, 0, 0);
                }
            }
        }
        #pragma unroll
        for (int mt = 0; mt < 4; ++mt)
            #pragma unroll
            for (int nt = 0; nt < 5; ++nt) {
                if (nt < ntiles) {
                    const int row = (tg0 + nt) * 16 + l15;   // SC row 0..143
                    const int t0  = cb + mt * 16 + l4 * 4;
                    s16x4 pk = { f2bf(sacc[mt][nt][0]), f2bf(sacc[mt][nt][1]),
                                 f2bf(sacc[mt][nt][2]), f2bf(sacc[mt][nt][3]) };
                    const int byt = (row * 512 + t0 * 2) ^ ((row & 7) << 4);
                    *(s16x4*)(SC + byt) = pk;
                }
            }
    }
    __syncthreads();

    // ---- phase 2: Toeplitz conv; coalesced btf loads, literal 2-slot prefetch ----
    f32x4 cacc[4][4];
    #pragma unroll
    for (int rt = 0; rt < 4; ++rt)
        #pragma unroll
        for (int n = 0; n < 4; ++n)
            cacc[rt][n] = (f32x4){0.f, 0.f, 0.f, 0.f};

    {
        const ushort* btw = btf + (size_t)(wc * 4) * 40 * 512 + lane * 8;

        s16x8 pb[2][4];
        auto ldB = [&](int st, int slot) {
            #pragma unroll
            for (int i = 0; i < 4; ++i)
                pb[slot][i] = *(const s16x8*)(btw + (size_t)(i * 40 + st) * 512);
        };
        auto convStep = [&](int st, int slot) {
            const int r = st >> 3, kb2 = (st & 7) * 64 + 16 * l4;
            __builtin_amdgcn_s_setprio(1);
            #pragma unroll
            for (int rt = 0; rt < 4; ++rt) {
                const int sr = wr * 64 + rt * 16 + l15 + r + 6;   // <= 137
                const s16x8 afr = *(const s16x8*)(SC + ((sr * 512 + kb2) ^ ((sr & 7) << 4)));
                #pragma unroll
                for (int n = 0; n < 4; ++n)
                    cacc[rt][n] = __builtin_amdgcn_mfma_f32_16x16x32_bf16(
                                      afr, pb[slot][n], cacc[rt][n], 0, 0, 0);
            }
            __builtin_amdgcn_s_setprio(0);
        };

        ldB(0, 0);
        for (int qq = 0; qq < 20; ++qq) {       // literal slots only (rule #20)
            const int st = qq * 2;
            ldB(st + 1, 1);
            convStep(st + 0, 0);
            if (st + 2 < 40) ldB(st + 2, 0);
            convStep(st + 1, 1);
        }
    }

    // ---- phase 2.5: + m (fragment-linear, consume each float4 immediately) ----
    {
        const float* mf = mfrag
            + ((((size_t)(bb * 2 + blockIdx.x)) * 8 + w) * 64 + lane) * 64;
        #pragma unroll
        for (int rt = 0; rt < 4; ++rt)
            #pragma unroll
            for (int n = 0; n < 4; ++n) {
                const float4 mv = *(const float4*)(mf + rt * 16 + n * 4);
                cacc[rt][n][0] += mv.x;
                cacc[rt][n][1] += mv.y;
                cacc[rt][n][2] += mv.z;
                cacc[rt][n][3] += mv.w;
            }
    }

    // ---- phase 3: single-barrier softmax (true wave max + (M,S) exchange) ----
    float wM[4][4];
    #pragma unroll
    for (int rt = 0; rt < 4; ++rt)
        #pragma unroll
        for (int rg = 0; rg < 4; ++rg) {
            float mx = fmaxf(fmaxf(cacc[rt][0][rg], cacc[rt][1][rg]),
                             fmaxf(cacc[rt][2][rg], cacc[rt][3][rg]));
            mx = fmaxf(mx, __shfl_xor(mx, 1));
            mx = fmaxf(mx, __shfl_xor(mx, 2));
            mx = fmaxf(mx, __shfl_xor(mx, 4));
            mx = fmaxf(mx, __shfl_xor(mx, 8));
            wM[rt][rg] = mx;
        }
    #pragma unroll
    for (int rt = 0; rt < 4; ++rt)
        #pragma unroll
        for (int n = 0; n < 4; ++n) {
            cacc[rt][n][0] = __expf(cacc[rt][n][0] - wM[rt][0]);
            cacc[rt][n][1] = __expf(cacc[rt][n][1] - wM[rt][1]);
            cacc[rt][n][2] = __expf(cacc[rt][n][2] - wM[rt][2]);
            cacc[rt][n][3] = __expf(cacc[rt][n][3] - wM[rt][3]);
        }
    #pragma unroll
    for (int rt = 0; rt < 4; ++rt)
        #pragma unroll
        for (int rg = 0; rg < 4; ++rg) {
            float s = cacc[rt][0][rg] + cacc[rt][1][rg]
                    + cacc[rt][2][rg] + cacc[rt][3][rg];
            s += __shfl_xor(s, 1);
            s += __shfl_xor(s, 2);
            s += __shfl_xor(s, 4);
            s += __shfl_xor(s, 8);
            if (l15 == 0) {
                const int row = wr * 64 + rt * 16 + l4 * 4 + rg;
                RED2[row * 8 + wc * 2 + 0] = wM[rt][rg];
                RED2[row * 8 + wc * 2 + 1] = s;
            }
        }
    __syncthreads();   // also guarantees all conv SC reads done (pre-PB write)

    // ---- combine + write P (bf16, swizzled, aliases SC rows 0..127) ----
    #pragma unroll
    for (int rt = 0; rt < 4; ++rt)
        #pragma unroll
        for (int rg = 0; rg < 4; ++rg) {
            const int row = wr * 64 + rt * 16 + l4 * 4 + rg;
            const float2 p0 = *(const float2*)&RED2[row * 8 + 0];
            const float2 p1 = *(const float2*)&RED2[row * 8 + 2];
            const float2 p2 = *(const float2*)&RED2[row * 8 + 4];
            const float2 p3 = *(const float2*)&RED2[row * 8 + 6];
            const float gM = fmaxf(fmaxf(p0.x, p1.x), fmaxf(p2.x, p3.x));
            const float tot = p0.y * __expf(p0.x - gM) + p1.y * __expf(p1.x - gM)
                            + p2.y * __expf(p2.x - gM) + p3.y * __expf(p3.x - gM);
            const float fac = __expf(wM[rt][rg] - gM) / tot;
            #pragma unroll
            for (int n = 0; n < 4; ++n) {
                const int col = cb + n * 16 + l15;
                const int byt = (row * 512 + col * 2) ^ ((row & 7) << 4);
                *(short*)(PB + byt) = f2bf(cacc[rt][n][rg] * fac);
            }
        }
    __syncthreads();

    // ---- phase 4: PV via MFMA; wave w -> rows w*16..w*16+15 ----
    const ushort* vf_h = vfrag + (size_t)head * 4 * 8 * 512 + lane * 8;
    f32x4 pacc[4];
    #pragma unroll
    for (int n = 0; n < 4; ++n) pacc[n] = (f32x4){0.f, 0.f, 0.f, 0.f};
    #pragma unroll
    for (int kk = 0; kk < 8; ++kk) {
        const int prow = w * 16 + l15;      // 0..127
        const int byta = (prow * 512 + kk * 64 + 16 * l4) ^ ((prow & 7) << 4);
        const s16x8 pa = *(const s16x8*)(PB + byta);
        #pragma unroll
        for (int n = 0; n < 4; ++n) {
            const s16x8 vb8 = *(const s16x8*)(vf_h + (size_t)(n * 8 + kk) * 512);
            pacc[n] = __builtin_amdgcn_mfma_f32_16x16x32_bf16(pa, vb8, pacc[n], 0, 0, 0);
        }
    }
    #pragma unroll
    for (int n = 0; n < 4; ++n)
        #pragma unroll
        for (int rg = 0; rg < 4; ++rg) {
            const int i = i0 + w * 16 + l4 * 4 + rg;
            const int d = n * 16 + l15;
            attn[(((size_t)bb * S + i) * H + hh) * DH + d] = (ushort)f2bf(pacc[n][rg]);
        }
}

// ---------------------------------------------------------------------------
// launcher (4 kernels)
// ---------------------------------------------------------------------------
extern "C" void kernel_launch(void* const* d_in, const int* in_sizes, int n_in,
                              void* d_out, int out_size, void* d_ws, size_t ws_size,
                              hipStream_t stream)
{
    (void)in_sizes; (void)n_in; (void)out_size; (void)ws_size;

    const float* x        = (const float*)d_in[0];
    const float* particles= (const float*)d_in[1];
    const float* wq       = (const float*)d_in[2];
    const float* wk       = (const float*)d_in[3];
    const float* wv       = (const float*)d_in[4];
    const float* dense_w  = (const float*)d_in[5];
    const float* dense_b  = (const float*)d_in[6];
    const float* c1k      = (const float*)d_in[7];
    const float* c1b      = (const float*)d_in[8];
    const float* c3k      = (const float*)d_in[9];
    const float* c3b      = (const float*)d_in[10];
    const float* c5k      = (const float*)d_in[11];
    const float* c5b      = (const float*)d_in[12];
    const float* mw1      = (const float*)d_in[13];
    const float* mb1      = (const float*)d_in[14];
    const float* mw2      = (const float*)d_in[15];
    const float* mb2      = (const float*)d_in[16];
    const float* mw3      = (const float*)d_in[17];
    const float* mb3      = (const float*)d_in[18];
    float* out = (float*)d_out;

    // workspace layout (ushort units unless noted), total ~104 MB
    ushort* xbf   = (ushort*)d_ws;                       //  8,388,608
    ushort* wt    = xbf   + (size_t)8388608;             //  1,048,576
    ushort* qb    = wt    + (size_t)1048576;             //  8,388,608
    ushort* kb    = qb    + (size_t)8388608;             //  8,388,608
    ushort* attnb = kb    + (size_t)8388608;             //  8,388,608
    ushort* btf   = attnb + (size_t)8388608;             //    327,680  frag-linear
    ushort* vfrag = btf   + (size_t)327680;              //  8,388,608  frag-linear
    float*  mfrag = (float*)(vfrag + (size_t)8388608);   //  4,194,304 f32 frag-linear

    prep_kernel<<<dim3(21664), 256, 0, stream>>>(
        x, xbf, wq, wk, wv, dense_w, wt,
        c1k, c3k, c5k, btf,
        particles, mw1, mb1, mw2, mb2, mw3, mb3, c1b, c3b, c5b, mfrag);

    gemm_qkv3_kernel<<<dim3(128, 4, 3), 256, 0, stream>>>(
        wt, xbf, qb, kb, vfrag);

    fused_mfma_kernel<<<dim3(2, BH), 512, 0, stream>>>(
        qb, kb, vfrag, btf, mfrag, attnb);

    gemm_dense_kernel<<<dim3(128, 4), 256, 0, stream>>>(
        wt + (size_t)3 * DD * DD, attnb, dense_b, out);
}